// Round 1
// baseline (5016.999 us; speedup 1.0000x reference)
//
#include <hip/hip_runtime.h>

#define B_ 2
#define S_ 2048
#define D_ 1024
#define H_ 16
#define DEPTH_ 64

// ---------------------------------------------------------------------------
// Generic tiled fp32 GEMM: C = A(MxK) * B(KxN) (+bias), batched via grid.z.
// Batch offsets: A += z*sA; B += (z/Hdiv)*sBb + (z%Hdiv)*sBh; C likewise.
// Tile 64x64, BK=16, 256 threads, 4x4 accum per thread.
// ---------------------------------------------------------------------------
#define BM 64
#define BN 64
#define BKK 16

__global__ __launch_bounds__(256) void gemm_bias(
    const float* __restrict__ A, const float* __restrict__ Bm,
    const float* __restrict__ bias, float* __restrict__ C,
    int M, int N, int K, int lda, int ldb, int ldc,
    long sA, long sBb, long sBh, long sCb, long sCh, int Hdiv)
{
    int bz = blockIdx.z;
    int bb = bz / Hdiv, hh = bz % Hdiv;
    const float* Ap = A + (long)bz * sA;
    const float* Bp = Bm + (long)bb * sBb + (long)hh * sBh;
    float*       Cp = C + (long)bb * sCb + (long)hh * sCh;

    __shared__ float As[BKK][BM + 4];
    __shared__ float Bs[BKK][BN + 4];

    int tid  = threadIdx.x;
    int row0 = blockIdx.y * BM, col0 = blockIdx.x * BN;
    int am = tid >> 2, ak = (tid & 3) << 2;   // A tile: 64 rows x 16 k
    int bk = tid >> 4, bn = (tid & 15) << 2;  // B tile: 16 k x 64 cols
    int tm = (tid >> 4) << 2, tn = (tid & 15) << 2;

    float acc[4][4] = {};

    for (int k0 = 0; k0 < K; k0 += BKK) {
        float4 av = *(const float4*)(Ap + (long)(row0 + am) * lda + k0 + ak);
        float4 bv = *(const float4*)(Bp + (long)(k0 + bk) * ldb + col0 + bn);
        As[ak + 0][am] = av.x;
        As[ak + 1][am] = av.y;
        As[ak + 2][am] = av.z;
        As[ak + 3][am] = av.w;
        *(float4*)&Bs[bk][bn] = bv;
        __syncthreads();
#pragma unroll
        for (int kk = 0; kk < BKK; ++kk) {
            float4 a = *(const float4*)&As[kk][tm];
            float4 b = *(const float4*)&Bs[kk][tn];
            float ar[4] = {a.x, a.y, a.z, a.w};
            float br[4] = {b.x, b.y, b.z, b.w};
#pragma unroll
            for (int i = 0; i < 4; ++i)
#pragma unroll
                for (int j = 0; j < 4; ++j) acc[i][j] += ar[i] * br[j];
        }
        __syncthreads();
    }

    float4 bvv = make_float4(0.f, 0.f, 0.f, 0.f);
    if (bias) bvv = *(const float4*)(bias + col0 + tn);
#pragma unroll
    for (int i = 0; i < 4; ++i) {
        float4 o;
        o.x = acc[i][0] + bvv.x;
        o.y = acc[i][1] + bvv.y;
        o.z = acc[i][2] + bvv.z;
        o.w = acc[i][3] + bvv.w;
        *(float4*)(Cp + (long)(row0 + tm + i) * ldc + col0 + tn) = o;
    }
}

// ---------------------------------------------------------------------------
// Scores + symmetric mask + softmax, writes normalized attn to global.
// One block = (b,h, 4 consecutive q rows). Full 2048-wide rows in LDS (32KB).
// ---------------------------------------------------------------------------
#define AROWS 4

__global__ __launch_bounds__(256) void attn_softmax(
    const float* __restrict__ q, const float* __restrict__ k,
    const float* __restrict__ mask, float* __restrict__ attn)
{
    int bh = blockIdx.y;
    int b  = bh >> 4;        // /H_
    int h  = bh & 15;
    int q0 = blockIdx.x * AROWS;
    int tid = threadIdx.x;

    __shared__ float qs[AROWS][DEPTH_];
    __shared__ float tile[AROWS][S_];

    // stage q rows (4 x 64 floats)
    const float* qbase = q + ((long)b * S_ + q0) * D_ + h * DEPTH_;
    for (int i = tid; i < AROWS * DEPTH_; i += 256) {
        int r = i >> 6, d = i & 63;
        qs[r][d] = qbase[(long)r * D_ + d];
    }
    float mq[AROWS];
#pragma unroll
    for (int r = 0; r < AROWS; ++r) mq[r] = mask[(long)b * S_ + q0 + r];
    __syncthreads();

    const float* kbase = k + (long)b * S_ * D_ + h * DEPTH_;
#pragma unroll
    for (int cc = 0; cc < S_ / 256; ++cc) {
        int c = cc * 256 + tid;
        float4 kv4[16];
        const float4* kr = (const float4*)(kbase + (long)c * D_);
#pragma unroll
        for (int i = 0; i < 16; ++i) kv4[i] = kr[i];
        float mk = mask[(long)b * S_ + c];
#pragma unroll
        for (int r = 0; r < AROWS; ++r) {
            float dot = 0.f;
#pragma unroll
            for (int i = 0; i < 16; ++i) {
                float4 qv = *(const float4*)&qs[r][4 * i];
                dot += qv.x * kv4[i].x + qv.y * kv4[i].y +
                       qv.z * kv4[i].z + qv.w * kv4[i].w;
            }
            tile[r][c] = dot * 0.125f + fminf(1.0f, mq[r] + mk);
        }
    }
    __syncthreads();

    // one wave per row: shuffle softmax + coalesced global write
    int wave = tid >> 6, lane = tid & 63;
    int r = wave;  // AROWS==4 waves
    float m = -1e30f;
    for (int c = lane; c < S_; c += 64) m = fmaxf(m, tile[r][c]);
#pragma unroll
    for (int off = 32; off; off >>= 1) m = fmaxf(m, __shfl_xor(m, off, 64));
    float s = 0.f;
    for (int c = lane; c < S_; c += 64) {
        float e = __expf(tile[r][c] - m);
        tile[r][c] = e;
        s += e;
    }
#pragma unroll
    for (int off = 32; off; off >>= 1) s += __shfl_xor(s, off, 64);
    float inv = 1.0f / s;
    float* arow = attn + ((long)bh * S_ + q0 + r) * S_;
    for (int c = lane; c < S_; c += 64) arow[c] = tile[r][c] * inv;
}

// ---------------------------------------------------------------------------
extern "C" void kernel_launch(void* const* d_in, const int* in_sizes, int n_in,
                              void* d_out, int out_size, void* d_ws, size_t ws_size,
                              hipStream_t stream)
{
    const float* x    = (const float*)d_in[0];
    const float* mask = (const float*)d_in[1];
    const float* Wq   = (const float*)d_in[2];
    const float* bq   = (const float*)d_in[3];
    const float* Wk   = (const float*)d_in[4];
    const float* bk   = (const float*)d_in[5];
    const float* Wv   = (const float*)d_in[6];
    const float* bv   = (const float*)d_in[7];
    const float* Wo   = (const float*)d_in[8];
    const float* bo   = (const float*)d_in[9];

    float* out  = (float*)d_out;                       // (B,S,D)
    float* attn = out + (size_t)B_ * S_ * D_;          // (B,H,S,S)

    size_t n = (size_t)B_ * S_ * D_;                   // 4,194,304
    float* q = (float*)d_ws;
    float* k = q + n;
    float* v = k + n;
    float* z = v + n;

    dim3 blk(256);
    const int M = B_ * S_;  // 4096

    // Q/K/V projections: (4096x1024) x (1024x1024) + bias
    gemm_bias<<<dim3(D_ / BN, M / BM, 1), blk, 0, stream>>>(
        x, Wq, bq, q, M, D_, D_, D_, D_, D_, 0, 0, 0, 0, 0, 1);
    gemm_bias<<<dim3(D_ / BN, M / BM, 1), blk, 0, stream>>>(
        x, Wk, bk, k, M, D_, D_, D_, D_, D_, 0, 0, 0, 0, 0, 1);
    gemm_bias<<<dim3(D_ / BN, M / BM, 1), blk, 0, stream>>>(
        x, Wv, bv, v, M, D_, D_, D_, D_, D_, 0, 0, 0, 0, 0, 1);

    // scores + mask + softmax -> attn (B,H,S,S)
    attn_softmax<<<dim3(S_ / AROWS, B_ * H_), blk, 0, stream>>>(q, k, mask, attn);

    // z = attn @ v : per (b,h) GEMM 2048x64x2048
    gemm_bias<<<dim3(1, S_ / BM, B_ * H_), blk, 0, stream>>>(
        attn, v, nullptr, z, S_, DEPTH_, S_, S_, D_, D_,
        (long)S_ * S_, (long)S_ * D_, DEPTH_, (long)S_ * D_, DEPTH_, H_);

    // out = z @ Wo + bo
    gemm_bias<<<dim3(D_ / BN, M / BM, 1), blk, 0, stream>>>(
        z, Wo, bo, out, M, D_, D_, D_, D_, D_, 0, 0, 0, 0, 0, 1);
}

// Round 2
// 1830.663 us; speedup vs baseline: 2.7405x; 2.7405x over previous
//
#include <hip/hip_runtime.h>

#define B_ 2
#define S_ 2048
#define D_ 1024
#define H_ 16
#define DEPTH_ 64

// XOR-swizzled float4-group index for transposed 64x64 LDS tiles (stride 64,
// 16B-aligned rows, conflict-free b128 reads AND scatter stores).
#define SWZ(g, d) ((((g) ^ ((d) & 15)) << 2))

// ---------------------------------------------------------------------------
// gemm128: C(4096x1024) = A(4096x1024) @ B(1024x1024) + bias. Tile 128x128x16,
// 256 threads, 8x8 accumulators/thread.
// ---------------------------------------------------------------------------
__global__ __launch_bounds__(256, 2) void gemm128(
    const float* __restrict__ A, const float* __restrict__ Bw,
    const float* __restrict__ bias, float* __restrict__ C)
{
    __shared__ float As[16][132];   // [k][row]
    __shared__ float Bs[16][132];   // [k][col]
    int t = threadIdx.x;
    int row0 = blockIdx.y * 128, col0 = blockIdx.x * 128;

    int ar = t >> 2, ak = (t & 3) << 2;    // A rows ar, ar+64; k offs ak..ak+3
    int bk = t >> 5, bc = (t & 31) << 2;   // B k rows bk, bk+8; cols bc..bc+3
    int tm = (t >> 4) << 3, tn = (t & 15) << 3;

    float acc[8][8] = {};

    for (int k0 = 0; k0 < 1024; k0 += 16) {
        float4 a0 = *(const float4*)(A + (long)(row0 + ar) * 1024 + k0 + ak);
        float4 a1 = *(const float4*)(A + (long)(row0 + ar + 64) * 1024 + k0 + ak);
        float4 b0 = *(const float4*)(Bw + (long)(k0 + bk) * 1024 + col0 + bc);
        float4 b1 = *(const float4*)(Bw + (long)(k0 + bk + 8) * 1024 + col0 + bc);
        As[ak + 0][ar] = a0.x; As[ak + 1][ar] = a0.y;
        As[ak + 2][ar] = a0.z; As[ak + 3][ar] = a0.w;
        As[ak + 0][ar + 64] = a1.x; As[ak + 1][ar + 64] = a1.y;
        As[ak + 2][ar + 64] = a1.z; As[ak + 3][ar + 64] = a1.w;
        *(float4*)&Bs[bk][bc] = b0;
        *(float4*)&Bs[bk + 8][bc] = b1;
        __syncthreads();
#pragma unroll
        for (int kk = 0; kk < 16; ++kk) {
            float4 x0 = *(const float4*)&As[kk][tm];
            float4 x1 = *(const float4*)&As[kk][tm + 4];
            float4 y0 = *(const float4*)&Bs[kk][tn];
            float4 y1 = *(const float4*)&Bs[kk][tn + 4];
            float xa[8] = {x0.x, x0.y, x0.z, x0.w, x1.x, x1.y, x1.z, x1.w};
            float yb[8] = {y0.x, y0.y, y0.z, y0.w, y1.x, y1.y, y1.z, y1.w};
#pragma unroll
            for (int i = 0; i < 8; ++i)
#pragma unroll
                for (int j = 0; j < 8; ++j) acc[i][j] += xa[i] * yb[j];
        }
        __syncthreads();
    }

    float4 bv0 = *(const float4*)(bias + col0 + tn);
    float4 bv1 = *(const float4*)(bias + col0 + tn + 4);
#pragma unroll
    for (int i = 0; i < 8; ++i) {
        float4 o0, o1;
        o0.x = acc[i][0] + bv0.x; o0.y = acc[i][1] + bv0.y;
        o0.z = acc[i][2] + bv0.z; o0.w = acc[i][3] + bv0.w;
        o1.x = acc[i][4] + bv1.x; o1.y = acc[i][5] + bv1.y;
        o1.z = acc[i][6] + bv1.z; o1.w = acc[i][7] + bv1.w;
        float* cp = C + (long)(row0 + tm + i) * 1024 + col0;
        *(float4*)(cp + tn) = o0;
        *(float4*)(cp + tn + 4) = o1;
    }
}

// ---------------------------------------------------------------------------
// scores: logits(b,h,q,k) = Q·K^T * 0.125 + min(1, mq+mk). 64x64 tile per
// block, contraction over DEPTH=64 entirely in LDS (both tiles transposed +
// swizzled for vector reads).
// ---------------------------------------------------------------------------
__global__ __launch_bounds__(256, 2) void scores(
    const float* __restrict__ q, const float* __restrict__ k,
    const float* __restrict__ mask, float* __restrict__ attn)
{
    __shared__ float Qs[64 * 64];   // [d][qrow] swizzled
    __shared__ float Ks[64 * 64];   // [d][krow] swizzled
    int t = threadIdx.x;
    int bh = blockIdx.z, b = bh >> 4, h = bh & 15;
    int q0 = blockIdx.y * 64, k0 = blockIdx.x * 64;

    int rr = t >> 4, c4 = (t & 15) << 2;
    const float* qb = q + (long)(b * S_ + q0) * D_ + h * DEPTH_;
    const float* kb = k + (long)(b * S_ + k0) * D_ + h * DEPTH_;
#pragma unroll
    for (int i = 0; i < 4; ++i) {
        int r = rr + 16 * i;
        float4 qv = *(const float4*)(qb + (long)r * D_ + c4);
        float4 kv = *(const float4*)(kb + (long)r * D_ + c4);
        int g = r >> 2, e = r & 3;
        Qs[(c4 + 0) * 64 + SWZ(g, c4 + 0) + e] = qv.x;
        Qs[(c4 + 1) * 64 + SWZ(g, c4 + 1) + e] = qv.y;
        Qs[(c4 + 2) * 64 + SWZ(g, c4 + 2) + e] = qv.z;
        Qs[(c4 + 3) * 64 + SWZ(g, c4 + 3) + e] = qv.w;
        Ks[(c4 + 0) * 64 + SWZ(g, c4 + 0) + e] = kv.x;
        Ks[(c4 + 1) * 64 + SWZ(g, c4 + 1) + e] = kv.y;
        Ks[(c4 + 2) * 64 + SWZ(g, c4 + 2) + e] = kv.z;
        Ks[(c4 + 3) * 64 + SWZ(g, c4 + 3) + e] = kv.w;
    }
    __syncthreads();

    int tm = (t >> 4) << 2, tn = (t & 15) << 2;
    int gm = tm >> 2, gn = tn >> 2;
    float acc[4][4] = {};
#pragma unroll
    for (int kk = 0; kk < 64; ++kk) {
        float4 qa = *(const float4*)&Qs[kk * 64 + SWZ(gm, kk)];
        float4 kv = *(const float4*)&Ks[kk * 64 + SWZ(gn, kk)];
        float xa[4] = {qa.x, qa.y, qa.z, qa.w};
        float yb[4] = {kv.x, kv.y, kv.z, kv.w};
#pragma unroll
        for (int i = 0; i < 4; ++i)
#pragma unroll
            for (int j = 0; j < 4; ++j) acc[i][j] += xa[i] * yb[j];
    }

    float mq[4];
#pragma unroll
    for (int i = 0; i < 4; ++i) mq[i] = mask[b * S_ + q0 + tm + i];
    float4 mk4 = *(const float4*)(mask + b * S_ + k0 + tn);
    float mk[4] = {mk4.x, mk4.y, mk4.z, mk4.w};
    float* op = attn + (long)bh * S_ * S_;
#pragma unroll
    for (int i = 0; i < 4; ++i) {
        float4 o;
        o.x = acc[i][0] * 0.125f + fminf(1.0f, mq[i] + mk[0]);
        o.y = acc[i][1] * 0.125f + fminf(1.0f, mq[i] + mk[1]);
        o.z = acc[i][2] * 0.125f + fminf(1.0f, mq[i] + mk[2]);
        o.w = acc[i][3] * 0.125f + fminf(1.0f, mq[i] + mk[3]);
        *(float4*)(op + (long)(q0 + tm + i) * S_ + k0 + tn) = o;
    }
}

// ---------------------------------------------------------------------------
// attn_av: phase 1 = per-row max & sumexp over logits (coalesced, in-regs);
// phase 2 = normalize logits -> attn (in place) and accumulate attn @ V -> z.
// Block = 64 q-rows of one (b,h).
// ---------------------------------------------------------------------------
__global__ __launch_bounds__(256, 2) void attn_av(
    float* __restrict__ attn, const float* __restrict__ v, float* __restrict__ z)
{
    __shared__ float Ps[64 * 64];   // [key][qrow] swizzled
    __shared__ float Vs[64 * 64];   // [key][d] direct
    __shared__ float m_s[64], linv_s[64];

    int t = threadIdx.x;
    int bh = blockIdx.y, b = bh >> 4, h = bh & 15;
    int q0 = blockIdx.x * 64;
    float* arow = attn + (long)bh * S_ * S_;

    // ---- phase 1: per-row m, 1/l ----
    int wv = t >> 6, lane = t & 63;
    for (int rr = 0; rr < 16; ++rr) {
        int r = wv * 16 + rr;
        const float* rowp = arow + (long)(q0 + r) * S_;
        float4 x[8];
#pragma unroll
        for (int j = 0; j < 8; ++j)
            x[j] = *(const float4*)(rowp + 4 * lane + 256 * j);
        float m = -1e30f;
#pragma unroll
        for (int j = 0; j < 8; ++j) {
            m = fmaxf(m, fmaxf(fmaxf(x[j].x, x[j].y), fmaxf(x[j].z, x[j].w)));
        }
#pragma unroll
        for (int off = 32; off; off >>= 1) m = fmaxf(m, __shfl_xor(m, off, 64));
        float s = 0.f;
#pragma unroll
        for (int j = 0; j < 8; ++j) {
            s += __expf(x[j].x - m) + __expf(x[j].y - m) +
                 __expf(x[j].z - m) + __expf(x[j].w - m);
        }
#pragma unroll
        for (int off = 32; off; off >>= 1) s += __shfl_xor(s, off, 64);
        if (lane == 0) { m_s[r] = m; linv_s[r] = 1.0f / s; }
    }
    __syncthreads();

    // ---- phase 2: normalize + write attn, accumulate @V ----
    int rr16 = t >> 4, c4 = (t & 15) << 2;
    int tm = (t >> 4) << 2, tn = (t & 15) << 2;
    int gm = tm >> 2;
    float acc[4][4] = {};

    for (int kt = 0; kt < 32; ++kt) {
        int k0 = kt * 64;
#pragma unroll
        for (int i = 0; i < 4; ++i) {
            int r = rr16 + 16 * i;
            float* lp = arow + (long)(q0 + r) * S_ + k0 + c4;
            float4 lg = *(float4*)lp;
            float mm = m_s[r], li = linv_s[r];
            float4 p;
            p.x = __expf(lg.x - mm) * li;
            p.y = __expf(lg.y - mm) * li;
            p.z = __expf(lg.z - mm) * li;
            p.w = __expf(lg.w - mm) * li;
            *(float4*)lp = p;
            int g = r >> 2, e = r & 3;
            Ps[(c4 + 0) * 64 + SWZ(g, c4 + 0) + e] = p.x;
            Ps[(c4 + 1) * 64 + SWZ(g, c4 + 1) + e] = p.y;
            Ps[(c4 + 2) * 64 + SWZ(g, c4 + 2) + e] = p.z;
            Ps[(c4 + 3) * 64 + SWZ(g, c4 + 3) + e] = p.w;
            // V tile: rows = keys, cols = depth (direct layout)
            float4 vv = *(const float4*)(v + (long)(b * S_ + k0 + r) * D_ + h * DEPTH_ + c4);
            *(float4*)&Vs[r * 64 + c4] = vv;
        }
        __syncthreads();
#pragma unroll
        for (int kk = 0; kk < 64; ++kk) {
            float4 pa = *(const float4*)&Ps[kk * 64 + SWZ(gm, kk)];
            float4 vb = *(const float4*)&Vs[kk * 64 + tn];
            float xa[4] = {pa.x, pa.y, pa.z, pa.w};
            float yb[4] = {vb.x, vb.y, vb.z, vb.w};
#pragma unroll
            for (int i = 0; i < 4; ++i)
#pragma unroll
                for (int j = 0; j < 4; ++j) acc[i][j] += xa[i] * yb[j];
        }
        __syncthreads();
    }

#pragma unroll
    for (int i = 0; i < 4; ++i) {
        float4 o;
        o.x = acc[i][0]; o.y = acc[i][1]; o.z = acc[i][2]; o.w = acc[i][3];
        *(float4*)(z + (long)(b * S_ + q0 + tm + i) * D_ + h * DEPTH_ + tn) = o;
    }
}

// ---------------------------------------------------------------------------
extern "C" void kernel_launch(void* const* d_in, const int* in_sizes, int n_in,
                              void* d_out, int out_size, void* d_ws, size_t ws_size,
                              hipStream_t stream)
{
    const float* x    = (const float*)d_in[0];
    const float* mask = (const float*)d_in[1];
    const float* Wq   = (const float*)d_in[2];
    const float* bq   = (const float*)d_in[3];
    const float* Wk   = (const float*)d_in[4];
    const float* bk   = (const float*)d_in[5];
    const float* Wv   = (const float*)d_in[6];
    const float* bv   = (const float*)d_in[7];
    const float* Wo   = (const float*)d_in[8];
    const float* bo   = (const float*)d_in[9];

    float* out  = (float*)d_out;                  // (B,S,D)
    float* attn = out + (size_t)B_ * S_ * D_;     // (B,H,S,S)

    size_t n = (size_t)B_ * S_ * D_;
    float* q = (float*)d_ws;
    float* k = q + n;
    float* v = k + n;
    float* z = v + n;

    dim3 blk(256);
    gemm128<<<dim3(8, 32), blk, 0, stream>>>(x, Wq, bq, q);
    gemm128<<<dim3(8, 32), blk, 0, stream>>>(x, Wk, bk, k);
    gemm128<<<dim3(8, 32), blk, 0, stream>>>(x, Wv, bv, v);

    scores<<<dim3(32, 32, 32), blk, 0, stream>>>(q, k, mask, attn);
    attn_av<<<dim3(32, 32), blk, 0, stream>>>(attn, v, z);

    gemm128<<<dim3(8, 32), blk, 0, stream>>>(z, Wo, bo, out);
}